// Round 2
// baseline (545.273 us; speedup 1.0000x reference)
//
#include <hip/hip_runtime.h>
#include <hip/hip_bf16.h>

#define SEQ 2048
#define SCALE 0.125f
#define LOG2E 1.4426950408889634f

typedef __bf16 bf16;
typedef __bf16 bf16x4 __attribute__((ext_vector_type(4)));
typedef __bf16 bf16x8 __attribute__((ext_vector_type(8)));
typedef float f32x4 __attribute__((ext_vector_type(4)));
typedef unsigned int u32;

__device__ __forceinline__ void gl_lds16(const void* g, void* l) {
    __builtin_amdgcn_global_load_lds((const __attribute__((address_space(1))) u32*)g,
                                     (__attribute__((address_space(3))) u32*)l, 16, 0, 0);
}

// ---------------- prep kernels ----------------

__global__ __launch_bounds__(256) void k_cast_x(const float4* __restrict__ x,
                                                bf16x4* __restrict__ xb) {
    int t = blockIdx.x * 256 + threadIdx.x;
    float4 f = x[t];
    bf16x4 o;
    o[0] = (bf16)f.x; o[1] = (bf16)f.y; o[2] = (bf16)f.z; o[3] = (bf16)f.w;
    xb[t] = o;
}

// src [1024][1024] fp32 -> dst [1024][1024] bf16 transposed: dst[c][r] = src[r][c]
__global__ __launch_bounds__(256) void k_transpose_cast(const float* __restrict__ src,
                                                        bf16* __restrict__ dst) {
    __shared__ float tile[32][33];
    int bx = blockIdx.x * 32;   // src col base
    int by = blockIdx.y * 32;   // src row base
    int tx = threadIdx.x;       // 0..31
    int ty = threadIdx.y;       // 0..7
#pragma unroll
    for (int j = 0; j < 32; j += 8)
        tile[ty + j][tx] = src[(size_t)(by + ty + j) * 1024 + bx + tx];
    __syncthreads();
#pragma unroll
    for (int j = 0; j < 32; j += 8)
        dst[(size_t)(bx + ty + j) * 1024 + by + tx] = (bf16)tile[tx][ty + j];
}

// ---------------- GEMM 1: QV = Xb @ [Wq|Wv] + bias, scatter epilogue ----------------

__global__ __launch_bounds__(256) void k_gemm_qv(const bf16* __restrict__ Xb,
                                                 const bf16* __restrict__ Wqvt,
                                                 const float* __restrict__ bq,
                                                 const float* __restrict__ bv,
                                                 bf16* __restrict__ Q,
                                                 bf16* __restrict__ Vt,
                                                 float* __restrict__ QN) {
    constexpr int K = 1024;
    __shared__ bf16 As[128 * 32];
    __shared__ bf16 Bs[128 * 32];
    int t = threadIdx.x, w = t >> 6, l = t & 63;
    int blockN = blockIdx.x * 128, blockM = blockIdx.y * 128;
    int wm = w & 1, wn = w >> 1;
    int lr = l & 15, quad = l >> 4, q8 = quad * 8;
    int skcol = (l & 3) * 8;

    f32x4 acc[4][4] = {};
    const bf16* Ab = Xb + (size_t)blockM * K;
    const bf16* Bb = Wqvt + (size_t)blockN * K;

    for (int k0 = 0; k0 < K; k0 += 32) {
#pragma unroll
        for (int c2 = 0; c2 < 2; ++c2) {
            int c = 2 * w + c2;
            int row = c * 16 + (l >> 2);
            gl_lds16(Ab + (size_t)row * K + k0 + skcol, As + c * 512);
            gl_lds16(Bb + (size_t)row * K + k0 + skcol, Bs + c * 512);
        }
        __syncthreads();
        const bf16* Aw = As + wm * 64 * 32;
        const bf16* Bw = Bs + wn * 64 * 32;
        bf16x8 af[4], bfr[4];
#pragma unroll
        for (int mi = 0; mi < 4; ++mi) af[mi] = *(const bf16x8*)(Aw + (mi * 16 + lr) * 32 + q8);
#pragma unroll
        for (int ni = 0; ni < 4; ++ni) bfr[ni] = *(const bf16x8*)(Bw + (ni * 16 + lr) * 32 + q8);
#pragma unroll
        for (int mi = 0; mi < 4; ++mi)
#pragma unroll
            for (int ni = 0; ni < 4; ++ni)
                acc[mi][ni] = __builtin_amdgcn_mfma_f32_16x16x32_bf16(af[mi], bfr[ni], acc[mi][ni], 0, 0, 0);
        __syncthreads();
    }

    int colbase = blockN + wn * 64;
    bool isQ = colbase < 1024;
    int h = ((isQ ? colbase : colbase - 1024) >> 6);
    float bias[4];
#pragma unroll
    for (int ni = 0; ni < 4; ++ni) {
        int col = colbase + ni * 16 + lr;
        bias[ni] = isQ ? bq[col] : bv[col - 1024];
    }
#pragma unroll
    for (int mi = 0; mi < 4; ++mi) {
#pragma unroll
        for (int r = 0; r < 4; ++r) {
            int m = blockM + wm * 64 + mi * 16 + quad * 4 + r;
            int b = m >> 11, s = m & 2047;
            int bh = (b << 4) + h;
            float qsq = 0.f;
#pragma unroll
            for (int ni = 0; ni < 4; ++ni) {
                float v = acc[mi][ni][r] + bias[ni];
                bf16 vb = (bf16)v;
                int dh = ni * 16 + lr;
                if (isQ) {
                    Q[((size_t)bh * SEQ + s) * 64 + dh] = vb;
                    float vr = (float)vb;
                    qsq += vr * vr;
                } else {
                    Vt[((size_t)bh * 64 + dh) * SEQ + s] = vb;
                }
            }
            if (isQ) {
                qsq += __shfl_xor(qsq, 1);
                qsq += __shfl_xor(qsq, 2);
                qsq += __shfl_xor(qsq, 4);
                qsq += __shfl_xor(qsq, 8);
                if (lr == 0) QN[(size_t)bh * SEQ + s] = qsq;
            }
        }
    }
}

// ---------------- attention v2: i-tile 128 (32 rows/wave), xor-swizzled LDS ----------------
// grid: x = 16 (i-tiles of 128 rows), y = 64 (b*h). 256 threads = 4 waves x 32 rows.
// LDS layout: row stride 64 bf16 (128B), 16B chunk index swizzled by (c ^ (row&7)).

__global__ __launch_bounds__(256, 4) void k_attn(const bf16* __restrict__ Q,
                                                 const bf16* __restrict__ Vt,
                                                 const float* __restrict__ QN,
                                                 bf16* __restrict__ AO) {
    __shared__ bf16 Ks[64 * 64];
    __shared__ bf16 Vs[64 * 64];
    __shared__ bf16 Ps[4][32 * 64];

    int t = threadIdx.x, w = t >> 6, l = t & 63;
    int bh = blockIdx.y;
    int i0 = blockIdx.x * 128;
    const bf16* Qh = Q + (size_t)bh * SEQ * 64;
    const bf16* Vh = Vt + (size_t)bh * 64 * SEQ;
    const float* BBh = QN + (size_t)bh * SEQ;
    int lr = l & 15, quad = l >> 4, q8 = quad * 8, lr7 = lr & 7;

    // Q A-frags direct from global (per-block Q tile is 16KB, read once)
    bf16x8 af[2][2];
#pragma unroll
    for (int mi = 0; mi < 2; ++mi)
#pragma unroll
        for (int kc = 0; kc < 2; ++kc)
            af[mi][kc] = *(const bf16x8*)(Qh + (size_t)(i0 + w * 32 + mi * 16 + lr) * 64 + kc * 32 + q8);

    f32x4 oacc[2][4] = {};
    float dpart[2][4] = {};

    // precomputed swizzled frag-read offsets (bf16 units), j0-independent
    int koff[2][4], poff[2][2];
#pragma unroll
    for (int kc = 0; kc < 2; ++kc) {
#pragma unroll
        for (int ni = 0; ni < 4; ++ni)
            koff[kc][ni] = (ni * 16 + lr) * 64 + (((kc * 4 + quad) ^ lr7) * 8);
#pragma unroll
        for (int mi = 0; mi < 2; ++mi)
            poff[kc][mi] = (mi * 16 + lr) * 64 + (((kc * 4 + quad) ^ lr7) * 8);
    }

    // staging decomposition: thread handles chunks idx = t, t+256 for K and V each
    int s_r0 = t >> 3, s_c0 = t & 7;
    int s_r1 = (t + 256) >> 3, s_c1 = t & 7;
    int s_l0 = s_r0 * 64 + ((s_c0 ^ (s_r0 & 7)) * 8);
    int s_l1 = s_r1 * 64 + ((s_c1 ^ (s_r1 & 7)) * 8);

    bf16* Pw = Ps[w];

    for (int j0 = 0; j0 < SEQ; j0 += 64) {
        __syncthreads();
        // stage K (=Q rows j0..j0+63) and V (Vt rows d=0..63, cols j0..j0+63)
        *(bf16x8*)(Ks + s_l0) = *(const bf16x8*)(Qh + (size_t)(j0 + s_r0) * 64 + s_c0 * 8);
        *(bf16x8*)(Ks + s_l1) = *(const bf16x8*)(Qh + (size_t)(j0 + s_r1) * 64 + s_c1 * 8);
        *(bf16x8*)(Vs + s_l0) = *(const bf16x8*)(Vh + (size_t)s_r0 * SEQ + j0 + s_c0 * 8);
        *(bf16x8*)(Vs + s_l1) = *(const bf16x8*)(Vh + (size_t)s_r1 * SEQ + j0 + s_c1 * 8);
        __syncthreads();

        float bbt[4];
#pragma unroll
        for (int ni = 0; ni < 4; ++ni) bbt[ni] = BBh[j0 + ni * 16 + lr] * (SCALE * LOG2E);

        // S = Q_i . Q_j : 32 rows x 64 cols per wave
        f32x4 sacc[2][4] = {};
#pragma unroll
        for (int kc = 0; kc < 2; ++kc) {
#pragma unroll
            for (int ni = 0; ni < 4; ++ni) {
                bf16x8 bk = *(const bf16x8*)(Ks + koff[kc][ni]);
#pragma unroll
                for (int mi = 0; mi < 2; ++mi)
                    sacc[mi][ni] = __builtin_amdgcn_mfma_f32_16x16x32_bf16(af[mi][kc], bk, sacc[mi][ni], 0, 0, 0);
            }
        }

        // P = exp2(2*AB*SCALE*LOG2E - BB*SCALE*LOG2E); denom accumulate; swizzled LDS write
#pragma unroll
        for (int mi = 0; mi < 2; ++mi) {
#pragma unroll
            for (int ni = 0; ni < 4; ++ni) {
#pragma unroll
                for (int rr = 0; rr < 4; ++rr) {
                    float p = __builtin_amdgcn_exp2f(sacc[mi][ni][rr] * (2.f * SCALE * LOG2E) - bbt[ni]);
                    dpart[mi][rr] += p;
                    int row = mi * 16 + quad * 4 + rr;
                    int col = ni * 16 + lr;
                    Pw[row * 64 + (((col >> 3) ^ (row & 7)) * 8) + (col & 7)] = (bf16)p;
                }
            }
        }

        // O += P @ V
#pragma unroll
        for (int kc = 0; kc < 2; ++kc) {
            bf16x8 ap[2];
#pragma unroll
            for (int mi = 0; mi < 2; ++mi) ap[mi] = *(const bf16x8*)(Pw + poff[kc][mi]);
#pragma unroll
            for (int di = 0; di < 4; ++di) {
                bf16x8 bv8 = *(const bf16x8*)(Vs + koff[kc][di]);
#pragma unroll
                for (int mi = 0; mi < 2; ++mi)
                    oacc[mi][di] = __builtin_amdgcn_mfma_f32_16x16x32_bf16(ap[mi], bv8, oacc[mi][di], 0, 0, 0);
            }
        }
    }

    // epilogue
    int b = bh >> 4, h = bh & 15;
#pragma unroll
    for (int mi = 0; mi < 2; ++mi) {
#pragma unroll
        for (int r = 0; r < 4; ++r) {
            float d = dpart[mi][r];
            d += __shfl_xor(d, 1);
            d += __shfl_xor(d, 2);
            d += __shfl_xor(d, 4);
            d += __shfl_xor(d, 8);
            float inv = 1.f / d;
            int s = i0 + w * 32 + mi * 16 + quad * 4 + r;
#pragma unroll
            for (int di = 0; di < 4; ++di) {
                AO[((size_t)(b * SEQ + s)) * 1024 + h * 64 + di * 16 + lr] = (bf16)(oacc[mi][di][r] * inv);
            }
        }
    }
}

// ---------------- GEMM 3: out = AO @ Wo + bo ----------------

__global__ __launch_bounds__(256) void k_gemm_out(const bf16* __restrict__ AO,
                                                  const bf16* __restrict__ Wot,
                                                  const float* __restrict__ bo,
                                                  float* __restrict__ out) {
    constexpr int K = 1024;
    __shared__ bf16 As[128 * 32];
    __shared__ bf16 Bs[128 * 32];
    int t = threadIdx.x, w = t >> 6, l = t & 63;
    int blockN = blockIdx.x * 128, blockM = blockIdx.y * 128;
    int wm = w & 1, wn = w >> 1;
    int lr = l & 15, quad = l >> 4, q8 = quad * 8;
    int skcol = (l & 3) * 8;

    f32x4 acc[4][4] = {};
    const bf16* Ab = AO + (size_t)blockM * K;
    const bf16* Bb = Wot + (size_t)blockN * K;

    for (int k0 = 0; k0 < K; k0 += 32) {
#pragma unroll
        for (int c2 = 0; c2 < 2; ++c2) {
            int c = 2 * w + c2;
            int row = c * 16 + (l >> 2);
            gl_lds16(Ab + (size_t)row * K + k0 + skcol, As + c * 512);
            gl_lds16(Bb + (size_t)row * K + k0 + skcol, Bs + c * 512);
        }
        __syncthreads();
        const bf16* Aw = As + wm * 64 * 32;
        const bf16* Bw = Bs + wn * 64 * 32;
        bf16x8 af[4], bfr[4];
#pragma unroll
        for (int mi = 0; mi < 4; ++mi) af[mi] = *(const bf16x8*)(Aw + (mi * 16 + lr) * 32 + q8);
#pragma unroll
        for (int ni = 0; ni < 4; ++ni) bfr[ni] = *(const bf16x8*)(Bw + (ni * 16 + lr) * 32 + q8);
#pragma unroll
        for (int mi = 0; mi < 4; ++mi)
#pragma unroll
            for (int ni = 0; ni < 4; ++ni)
                acc[mi][ni] = __builtin_amdgcn_mfma_f32_16x16x32_bf16(af[mi], bfr[ni], acc[mi][ni], 0, 0, 0);
        __syncthreads();
    }

    int colbase = blockN + wn * 64;
    float bias[4];
#pragma unroll
    for (int ni = 0; ni < 4; ++ni) bias[ni] = bo[colbase + ni * 16 + lr];
#pragma unroll
    for (int mi = 0; mi < 4; ++mi) {
#pragma unroll
        for (int r = 0; r < 4; ++r) {
            int m = blockM + wm * 64 + mi * 16 + quad * 4 + r;
#pragma unroll
            for (int ni = 0; ni < 4; ++ni) {
                out[(size_t)m * 1024 + colbase + ni * 16 + lr] = acc[mi][ni][r] + bias[ni];
            }
        }
    }
}

// ---------------- launch ----------------

extern "C" void kernel_launch(void* const* d_in, const int* in_sizes, int n_in,
                              void* d_out, int out_size, void* d_ws, size_t ws_size,
                              hipStream_t stream) {
    const float* x  = (const float*)d_in[0];
    const float* Wq = (const float*)d_in[1];
    const float* bq = (const float*)d_in[2];
    const float* Wv = (const float*)d_in[3];
    const float* bv = (const float*)d_in[4];
    const float* Wo = (const float*)d_in[5];
    const float* bo = (const float*)d_in[6];
    float* out = (float*)d_out;

    char* ws = (char*)d_ws;
    bf16* Xb   = (bf16*)ws;                          // 16 MB (reused as AO after GEMM1)
    bf16* Wqvt = (bf16*)(ws + (size_t)(16 << 20));   // 4 MB
    bf16* Wot  = (bf16*)(ws + (size_t)(20 << 20));   // 2 MB
    bf16* Qb   = (bf16*)(ws + (size_t)(22 << 20));   // 16 MB
    bf16* Vtb  = (bf16*)(ws + (size_t)(38 << 20));   // 16 MB
    float* QN  = (float*)(ws + (size_t)(54 << 20));  // 0.5 MB
    bf16* AO   = Xb;                                 // reuse: Xb dead after GEMM1

    k_cast_x<<<8192, 256, 0, stream>>>((const float4*)x, (bf16x4*)Xb);
    dim3 tb(32, 8);
    k_transpose_cast<<<dim3(32, 32), tb, 0, stream>>>(Wq, Wqvt);
    k_transpose_cast<<<dim3(32, 32), tb, 0, stream>>>(Wv, Wqvt + 1024 * 1024);
    k_transpose_cast<<<dim3(32, 32), tb, 0, stream>>>(Wo, Wot);
    k_gemm_qv<<<dim3(16, 64), 256, 0, stream>>>(Xb, Wqvt, bq, bv, Qb, Vtb, QN);
    k_attn<<<dim3(16, 64), 256, 0, stream>>>(Qb, Vtb, QN, AO);
    k_gemm_out<<<dim3(8, 64), 256, 0, stream>>>(AO, Wot, bo, out);
}

// Round 3
// 307.067 us; speedup vs baseline: 1.7757x; 1.7757x over previous
//
#include <hip/hip_runtime.h>
#include <hip/hip_bf16.h>

#define SEQ 2048
#define SCALE 0.125f
#define LOG2E 1.4426950408889634f

typedef __bf16 bf16;
typedef __bf16 bf16x4 __attribute__((ext_vector_type(4)));
typedef __bf16 bf16x8 __attribute__((ext_vector_type(8)));
typedef float f32x4 __attribute__((ext_vector_type(4)));
typedef unsigned int u32;

__device__ __forceinline__ void gl_lds16(const void* g, void* l) {
    __builtin_amdgcn_global_load_lds((const __attribute__((address_space(1))) u32*)g,
                                     (__attribute__((address_space(3))) u32*)l, 16, 0, 0);
}

// ---------------- prep kernels ----------------

__global__ __launch_bounds__(256) void k_cast_x(const float4* __restrict__ x,
                                                bf16x4* __restrict__ xb) {
    int t = blockIdx.x * 256 + threadIdx.x;
    float4 f = x[t];
    bf16x4 o;
    o[0] = (bf16)f.x; o[1] = (bf16)f.y; o[2] = (bf16)f.z; o[3] = (bf16)f.w;
    xb[t] = o;
}

__global__ __launch_bounds__(256) void k_transpose_cast(const float* __restrict__ src,
                                                        bf16* __restrict__ dst) {
    __shared__ float tile[32][33];
    int bx = blockIdx.x * 32;
    int by = blockIdx.y * 32;
    int tx = threadIdx.x;
    int ty = threadIdx.y;
#pragma unroll
    for (int j = 0; j < 32; j += 8)
        tile[ty + j][tx] = src[(size_t)(by + ty + j) * 1024 + bx + tx];
    __syncthreads();
#pragma unroll
    for (int j = 0; j < 32; j += 8)
        dst[(size_t)(bx + ty + j) * 1024 + by + tx] = (bf16)tile[tx][ty + j];
}

// ---------------- GEMM 1: QV = Xb @ [Wq|Wv] + bias ----------------
// Q blocks (blockN<1024): C = A*B^T, epilogue -> Q[bh][s][dh] + row norms QN.
// V blocks: C^T = B*A^T via swapped MFMA operands -> registers hold Vt tiles,
// epilogue -> Vt[bh][dh][s] with coalesced 32B segments (no scatter).

__global__ __launch_bounds__(256) void k_gemm_qv(const bf16* __restrict__ Xb,
                                                 const bf16* __restrict__ Wqvt,
                                                 const float* __restrict__ bq,
                                                 const float* __restrict__ bv,
                                                 bf16* __restrict__ Q,
                                                 bf16* __restrict__ Vt,
                                                 float* __restrict__ QN) {
    constexpr int K = 1024;
    __shared__ bf16 As[128 * 32];
    __shared__ bf16 Bs[128 * 32];
    int t = threadIdx.x, w = t >> 6, l = t & 63;
    int blockN = blockIdx.x * 128, blockM = blockIdx.y * 128;
    int wm = w & 1, wn = w >> 1;
    int lr = l & 15, quad = l >> 4, q8 = quad * 8;
    int skcol = (l & 3) * 8;
    bool isQ = blockN < 1024;

    f32x4 acc[4][4] = {};
    const bf16* Ab = Xb + (size_t)blockM * K;
    const bf16* Bb = Wqvt + (size_t)blockN * K;

    for (int k0 = 0; k0 < K; k0 += 32) {
#pragma unroll
        for (int c2 = 0; c2 < 2; ++c2) {
            int c = 2 * w + c2;
            int row = c * 16 + (l >> 2);
            gl_lds16(Ab + (size_t)row * K + k0 + skcol, As + c * 512);
            gl_lds16(Bb + (size_t)row * K + k0 + skcol, Bs + c * 512);
        }
        __syncthreads();
        const bf16* Aw = As + wm * 64 * 32;
        const bf16* Bw = Bs + wn * 64 * 32;
        bf16x8 af[4], bfr[4];
#pragma unroll
        for (int mi = 0; mi < 4; ++mi) af[mi] = *(const bf16x8*)(Aw + (mi * 16 + lr) * 32 + q8);
#pragma unroll
        for (int ni = 0; ni < 4; ++ni) bfr[ni] = *(const bf16x8*)(Bw + (ni * 16 + lr) * 32 + q8);
        if (isQ) {
#pragma unroll
            for (int mi = 0; mi < 4; ++mi)
#pragma unroll
                for (int ni = 0; ni < 4; ++ni)
                    acc[mi][ni] = __builtin_amdgcn_mfma_f32_16x16x32_bf16(af[mi], bfr[ni], acc[mi][ni], 0, 0, 0);
        } else {
#pragma unroll
            for (int mi = 0; mi < 4; ++mi)
#pragma unroll
                for (int ni = 0; ni < 4; ++ni)
                    acc[mi][ni] = __builtin_amdgcn_mfma_f32_16x16x32_bf16(bfr[ni], af[mi], acc[mi][ni], 0, 0, 0);
        }
        __syncthreads();
    }

    int colbase = blockN + wn * 64;
    if (isQ) {
        int h = colbase >> 6;
        float bias[4];
#pragma unroll
        for (int ni = 0; ni < 4; ++ni) bias[ni] = bq[colbase + ni * 16 + lr];
#pragma unroll
        for (int mi = 0; mi < 4; ++mi) {
#pragma unroll
            for (int r = 0; r < 4; ++r) {
                int m = blockM + wm * 64 + mi * 16 + quad * 4 + r;
                int b = m >> 11, s = m & 2047;
                int bh = (b << 4) + h;
                float qsq = 0.f;
#pragma unroll
                for (int ni = 0; ni < 4; ++ni) {
                    float v = acc[mi][ni][r] + bias[ni];
                    bf16 vb = (bf16)v;
                    Q[((size_t)bh * SEQ + s) * 64 + ni * 16 + lr] = vb;
                    float vr = (float)vb;
                    qsq += vr * vr;
                }
                qsq += __shfl_xor(qsq, 1);
                qsq += __shfl_xor(qsq, 2);
                qsq += __shfl_xor(qsq, 4);
                qsq += __shfl_xor(qsq, 8);
                if (lr == 0) QN[(size_t)bh * SEQ + s] = qsq;
            }
        }
    } else {
        int h = (colbase - 1024) >> 6;
        int b = blockM >> 11;            // uniform within block (blockM 128-aligned)
        int bh = (b << 4) + h;
        int s_base = (blockM & 2047) + wm * 64;
        const float* bvh = bv + (colbase - 1024);
#pragma unroll
        for (int ni = 0; ni < 4; ++ni) {
#pragma unroll
            for (int r = 0; r < 4; ++r) {
                int dh = ni * 16 + quad * 4 + r;          // varies with quad
                float bias = bvh[dh];
#pragma unroll
                for (int mi = 0; mi < 4; ++mi) {
                    int s = s_base + mi * 16 + lr;
                    Vt[((size_t)bh * 64 + dh) * SEQ + s] = (bf16)(acc[mi][ni][r] + bias);
                }
            }
        }
    }
}

// ---------------- attention v3: 32 rows/wave, transient sacc, swizzled LDS ----------------
// grid: x = 16 (i-tiles of 128 rows), y = 64 (b*h). 256 threads = 4 waves x 32 rows.
// LDS rows of 64 bf16 (128B); 16B-chunk index swizzled by (c ^ (row&7)).

__global__ __launch_bounds__(256, 3) void k_attn(const bf16* __restrict__ Q,
                                                 const bf16* __restrict__ Vt,
                                                 const float* __restrict__ QN,
                                                 bf16* __restrict__ AO) {
    __shared__ bf16 Ks[64 * 64];
    __shared__ bf16 Vs[64 * 64];
    __shared__ bf16 Ps[4][32 * 64];
    __shared__ float BBl[2048];

    int t = threadIdx.x, w = t >> 6, l = t & 63;
    int bh = blockIdx.y;
    int i0 = blockIdx.x * 128;
    const bf16* Qh = Q + (size_t)bh * SEQ * 64;
    const bf16* Vh = Vt + (size_t)bh * 64 * SEQ;
    int lr = l & 15, quad = l >> 4, q8 = quad * 8, lr7 = lr & 7;

    // stage pre-scaled BB (softmax bias term) once
    {
        const float4* QN4 = (const float4*)(QN + (size_t)bh * SEQ);
        float4* BB4 = (float4*)BBl;
#pragma unroll
        for (int i = 0; i < 2; ++i) {
            float4 v = QN4[t + i * 256];
            v.x *= (SCALE * LOG2E); v.y *= (SCALE * LOG2E);
            v.z *= (SCALE * LOG2E); v.w *= (SCALE * LOG2E);
            BB4[t + i * 256] = v;
        }
    }

    // Q A-frags direct from global (16KB/block, read once)
    bf16x8 af[2][2];
#pragma unroll
    for (int mi = 0; mi < 2; ++mi)
#pragma unroll
        for (int kc = 0; kc < 2; ++kc)
            af[mi][kc] = *(const bf16x8*)(Qh + (size_t)(i0 + w * 32 + mi * 16 + lr) * 64 + kc * 32 + q8);

    f32x4 oacc[2][4] = {};
    float dpart[2][4] = {};

    // swizzled frag offsets (bf16 units): row*64 + ((kchunk ^ (row&7))*8)
    int koff[2][4], poff[2][2];
#pragma unroll
    for (int kc = 0; kc < 2; ++kc) {
#pragma unroll
        for (int ni = 0; ni < 4; ++ni)
            koff[kc][ni] = (ni * 16 + lr) * 64 + (((kc * 4 + quad) ^ lr7) * 8);
#pragma unroll
        for (int mi = 0; mi < 2; ++mi)
            poff[kc][mi] = (mi * 16 + lr) * 64 + (((kc * 4 + quad) ^ lr7) * 8);
    }

    // staging: thread handles 16B chunks t and t+256 (rows 0..31 / 32..63)
    int s_r0 = t >> 3, s_c0 = t & 7;
    int s_r1 = s_r0 + 32;
    int s_l0 = s_r0 * 64 + ((s_c0 ^ (s_r0 & 7)) * 8);
    int s_l1 = s_r1 * 64 + ((s_c0 ^ (s_r1 & 7)) * 8);

    bf16* Pw = Ps[w];

    for (int j0 = 0; j0 < SEQ; j0 += 64) {
        __syncthreads();
        *(bf16x8*)(Ks + s_l0) = *(const bf16x8*)(Qh + (size_t)(j0 + s_r0) * 64 + s_c0 * 8);
        *(bf16x8*)(Ks + s_l1) = *(const bf16x8*)(Qh + (size_t)(j0 + s_r1) * 64 + s_c0 * 8);
        *(bf16x8*)(Vs + s_l0) = *(const bf16x8*)(Vh + (size_t)s_r0 * SEQ + j0 + s_c0 * 8);
        *(bf16x8*)(Vs + s_l1) = *(const bf16x8*)(Vh + (size_t)s_r1 * SEQ + j0 + s_c0 * 8);
        __syncthreads();

        // S and P, one ni (16 j-cols) at a time -> sacc stays transient (8 regs)
#pragma unroll
        for (int ni = 0; ni < 4; ++ni) {
            float bbt = BBl[j0 + ni * 16 + lr];
            bf16x8 bk0 = *(const bf16x8*)(Ks + koff[0][ni]);
            bf16x8 bk1 = *(const bf16x8*)(Ks + koff[1][ni]);
            f32x4 s0 = {}, s1 = {};
            s0 = __builtin_amdgcn_mfma_f32_16x16x32_bf16(af[0][0], bk0, s0, 0, 0, 0);
            s0 = __builtin_amdgcn_mfma_f32_16x16x32_bf16(af[0][1], bk1, s0, 0, 0, 0);
            s1 = __builtin_amdgcn_mfma_f32_16x16x32_bf16(af[1][0], bk0, s1, 0, 0, 0);
            s1 = __builtin_amdgcn_mfma_f32_16x16x32_bf16(af[1][1], bk1, s1, 0, 0, 0);
#pragma unroll
            for (int rr = 0; rr < 4; ++rr) {
                float p0 = __builtin_amdgcn_exp2f(s0[rr] * (2.f * SCALE * LOG2E) - bbt);
                float p1 = __builtin_amdgcn_exp2f(s1[rr] * (2.f * SCALE * LOG2E) - bbt);
                dpart[0][rr] += p0;
                dpart[1][rr] += p1;
                int row0 = quad * 4 + rr;
                int row1 = 16 + row0;
                Pw[row0 * 64 + (((ni * 2 + (lr >> 3)) ^ (row0 & 7)) * 8) + (lr & 7)] = (bf16)p0;
                Pw[row1 * 64 + (((ni * 2 + (lr >> 3)) ^ (row1 & 7)) * 8) + (lr & 7)] = (bf16)p1;
            }
        }

        // O += P @ V  (P written/read by the same wave -> no barrier needed)
#pragma unroll
        for (int kc = 0; kc < 2; ++kc) {
            bf16x8 ap0 = *(const bf16x8*)(Pw + poff[kc][0]);
            bf16x8 ap1 = *(const bf16x8*)(Pw + poff[kc][1]);
#pragma unroll
            for (int di = 0; di < 4; ++di) {
                bf16x8 bv8 = *(const bf16x8*)(Vs + koff[kc][di]);
                oacc[0][di] = __builtin_amdgcn_mfma_f32_16x16x32_bf16(ap0, bv8, oacc[0][di], 0, 0, 0);
                oacc[1][di] = __builtin_amdgcn_mfma_f32_16x16x32_bf16(ap1, bv8, oacc[1][di], 0, 0, 0);
            }
        }
    }

    // epilogue
    int b = bh >> 4, h = bh & 15;
#pragma unroll
    for (int mi = 0; mi < 2; ++mi) {
#pragma unroll
        for (int r = 0; r < 4; ++r) {
            float d = dpart[mi][r];
            d += __shfl_xor(d, 1);
            d += __shfl_xor(d, 2);
            d += __shfl_xor(d, 4);
            d += __shfl_xor(d, 8);
            float inv = 1.f / d;
            int s = i0 + w * 32 + mi * 16 + quad * 4 + r;
#pragma unroll
            for (int di = 0; di < 4; ++di) {
                AO[((size_t)(b * SEQ + s)) * 1024 + h * 64 + di * 16 + lr] = (bf16)(oacc[mi][di][r] * inv);
            }
        }
    }
}

// ---------------- GEMM 3: out = AO @ Wo + bo ----------------

__global__ __launch_bounds__(256) void k_gemm_out(const bf16* __restrict__ AO,
                                                  const bf16* __restrict__ Wot,
                                                  const float* __restrict__ bo,
                                                  float* __restrict__ out) {
    constexpr int K = 1024;
    __shared__ bf16 As[128 * 32];
    __shared__ bf16 Bs[128 * 32];
    int t = threadIdx.x, w = t >> 6, l = t & 63;
    int blockN = blockIdx.x * 128, blockM = blockIdx.y * 128;
    int wm = w & 1, wn = w >> 1;
    int lr = l & 15, quad = l >> 4, q8 = quad * 8;
    int skcol = (l & 3) * 8;

    f32x4 acc[4][4] = {};
    const bf16* Ab = AO + (size_t)blockM * K;
    const bf16* Bb = Wot + (size_t)blockN * K;

    for (int k0 = 0; k0 < K; k0 += 32) {
#pragma unroll
        for (int c2 = 0; c2 < 2; ++c2) {
            int c = 2 * w + c2;
            int row = c * 16 + (l >> 2);
            gl_lds16(Ab + (size_t)row * K + k0 + skcol, As + c * 512);
            gl_lds16(Bb + (size_t)row * K + k0 + skcol, Bs + c * 512);
        }
        __syncthreads();
        const bf16* Aw = As + wm * 64 * 32;
        const bf16* Bw = Bs + wn * 64 * 32;
        bf16x8 af[4], bfr[4];
#pragma unroll
        for (int mi = 0; mi < 4; ++mi) af[mi] = *(const bf16x8*)(Aw + (mi * 16 + lr) * 32 + q8);
#pragma unroll
        for (int ni = 0; ni < 4; ++ni) bfr[ni] = *(const bf16x8*)(Bw + (ni * 16 + lr) * 32 + q8);
#pragma unroll
        for (int mi = 0; mi < 4; ++mi)
#pragma unroll
            for (int ni = 0; ni < 4; ++ni)
                acc[mi][ni] = __builtin_amdgcn_mfma_f32_16x16x32_bf16(af[mi], bfr[ni], acc[mi][ni], 0, 0, 0);
        __syncthreads();
    }

    int colbase = blockN + wn * 64;
    float bias[4];
#pragma unroll
    for (int ni = 0; ni < 4; ++ni) bias[ni] = bo[colbase + ni * 16 + lr];
#pragma unroll
    for (int mi = 0; mi < 4; ++mi) {
#pragma unroll
        for (int r = 0; r < 4; ++r) {
            int m = blockM + wm * 64 + mi * 16 + quad * 4 + r;
#pragma unroll
            for (int ni = 0; ni < 4; ++ni) {
                out[(size_t)m * 1024 + colbase + ni * 16 + lr] = acc[mi][ni][r] + bias[ni];
            }
        }
    }
}

// ---------------- launch ----------------

extern "C" void kernel_launch(void* const* d_in, const int* in_sizes, int n_in,
                              void* d_out, int out_size, void* d_ws, size_t ws_size,
                              hipStream_t stream) {
    const float* x  = (const float*)d_in[0];
    const float* Wq = (const float*)d_in[1];
    const float* bq = (const float*)d_in[2];
    const float* Wv = (const float*)d_in[3];
    const float* bv = (const float*)d_in[4];
    const float* Wo = (const float*)d_in[5];
    const float* bo = (const float*)d_in[6];
    float* out = (float*)d_out;

    char* ws = (char*)d_ws;
    bf16* Xb   = (bf16*)ws;                          // 16 MB (reused as AO)
    bf16* Wqvt = (bf16*)(ws + (size_t)(16 << 20));   // 4 MB
    bf16* Wot  = (bf16*)(ws + (size_t)(20 << 20));   // 2 MB
    bf16* Qb   = (bf16*)(ws + (size_t)(22 << 20));   // 16 MB
    bf16* Vtb  = (bf16*)(ws + (size_t)(38 << 20));   // 16 MB
    float* QN  = (float*)(ws + (size_t)(54 << 20));  // 0.5 MB
    bf16* AO   = Xb;

    k_cast_x<<<8192, 256, 0, stream>>>((const float4*)x, (bf16x4*)Xb);
    dim3 tb(32, 8);
    k_transpose_cast<<<dim3(32, 32), tb, 0, stream>>>(Wq, Wqvt);
    k_transpose_cast<<<dim3(32, 32), tb, 0, stream>>>(Wv, Wqvt + 1024 * 1024);
    k_transpose_cast<<<dim3(32, 32), tb, 0, stream>>>(Wo, Wot);
    k_gemm_qv<<<dim3(16, 64), 256, 0, stream>>>(Xb, Wqvt, bq, bv, Qb, Vtb, QN);
    k_attn<<<dim3(16, 64), 256, 0, stream>>>(Qb, Vtb, QN, AO);
    k_gemm_out<<<dim3(8, 64), 256, 0, stream>>>(AO, Wot, bo, out);
}

// Round 5
// 306.969 us; speedup vs baseline: 1.7763x; 1.0003x over previous
//
#include <hip/hip_runtime.h>
#include <hip/hip_bf16.h>

#define SEQ 2048
#define SCALE 0.125f
#define LOG2E 1.4426950408889634f

typedef __bf16 bf16;
typedef __bf16 bf16x4 __attribute__((ext_vector_type(4)));
typedef __bf16 bf16x8 __attribute__((ext_vector_type(8)));
typedef _Float16 f16;
typedef _Float16 f16x2 __attribute__((ext_vector_type(2)));
typedef _Float16 f16x4 __attribute__((ext_vector_type(4)));
typedef float f32x4 __attribute__((ext_vector_type(4)));
typedef unsigned int u32;
typedef unsigned int u32x4 __attribute__((ext_vector_type(4)));

__device__ __forceinline__ f16x2 pk_f16(float a, float b) {
    return __builtin_bit_cast(f16x2, __builtin_amdgcn_cvt_pkrtz(a, b));
}

__device__ __forceinline__ void gl_lds16(const void* g, void* l) {
    __builtin_amdgcn_global_load_lds((const __attribute__((address_space(1))) u32*)g,
                                     (__attribute__((address_space(3))) u32*)l, 16, 0, 0);
}

// ---------------- prep kernels ----------------

__global__ __launch_bounds__(256) void k_cast_x(const float4* __restrict__ x,
                                                bf16x4* __restrict__ xb) {
    int t = blockIdx.x * 256 + threadIdx.x;
    float4 f = x[t];
    bf16x4 o;
    o[0] = (bf16)f.x; o[1] = (bf16)f.y; o[2] = (bf16)f.z; o[3] = (bf16)f.w;
    xb[t] = o;
}

__global__ __launch_bounds__(256) void k_transpose_cast(const float* __restrict__ src,
                                                        bf16* __restrict__ dst) {
    __shared__ float tile[32][33];
    int bx = blockIdx.x * 32;
    int by = blockIdx.y * 32;
    int tx = threadIdx.x;
    int ty = threadIdx.y;
#pragma unroll
    for (int j = 0; j < 32; j += 8)
        tile[ty + j][tx] = src[(size_t)(by + ty + j) * 1024 + bx + tx];
    __syncthreads();
#pragma unroll
    for (int j = 0; j < 32; j += 8)
        dst[(size_t)(bx + ty + j) * 1024 + by + tx] = (bf16)tile[tx][ty + j];
}

// ---------------- GEMM 1: QV = Xb @ [Wq|Wv] + bias ----------------
// Q blocks: C = A*B^T -> Q[bh][s][dh] (bf16) + row norms QN.
// V blocks: swapped operands -> registers hold Vt tiles -> Vt[bh][dh][s] in f16.

__global__ __launch_bounds__(256) void k_gemm_qv(const bf16* __restrict__ Xb,
                                                 const bf16* __restrict__ Wqvt,
                                                 const float* __restrict__ bq,
                                                 const float* __restrict__ bv,
                                                 bf16* __restrict__ Q,
                                                 f16* __restrict__ Vt,
                                                 float* __restrict__ QN) {
    constexpr int K = 1024;
    __shared__ bf16 As[128 * 32];
    __shared__ bf16 Bs[128 * 32];
    int t = threadIdx.x, w = t >> 6, l = t & 63;
    int blockN = blockIdx.x * 128, blockM = blockIdx.y * 128;
    int wm = w & 1, wn = w >> 1;
    int lr = l & 15, quad = l >> 4, q8 = quad * 8;
    int skcol = (l & 3) * 8;
    bool isQ = blockN < 1024;

    f32x4 acc[4][4] = {};
    const bf16* Ab = Xb + (size_t)blockM * K;
    const bf16* Bb = Wqvt + (size_t)blockN * K;

    for (int k0 = 0; k0 < K; k0 += 32) {
#pragma unroll
        for (int c2 = 0; c2 < 2; ++c2) {
            int c = 2 * w + c2;
            int row = c * 16 + (l >> 2);
            gl_lds16(Ab + (size_t)row * K + k0 + skcol, As + c * 512);
            gl_lds16(Bb + (size_t)row * K + k0 + skcol, Bs + c * 512);
        }
        __syncthreads();
        const bf16* Aw = As + wm * 64 * 32;
        const bf16* Bw = Bs + wn * 64 * 32;
        bf16x8 af[4], bfr[4];
#pragma unroll
        for (int mi = 0; mi < 4; ++mi) af[mi] = *(const bf16x8*)(Aw + (mi * 16 + lr) * 32 + q8);
#pragma unroll
        for (int ni = 0; ni < 4; ++ni) bfr[ni] = *(const bf16x8*)(Bw + (ni * 16 + lr) * 32 + q8);
        if (isQ) {
#pragma unroll
            for (int mi = 0; mi < 4; ++mi)
#pragma unroll
                for (int ni = 0; ni < 4; ++ni)
                    acc[mi][ni] = __builtin_amdgcn_mfma_f32_16x16x32_bf16(af[mi], bfr[ni], acc[mi][ni], 0, 0, 0);
        } else {
#pragma unroll
            for (int mi = 0; mi < 4; ++mi)
#pragma unroll
                for (int ni = 0; ni < 4; ++ni)
                    acc[mi][ni] = __builtin_amdgcn_mfma_f32_16x16x32_bf16(bfr[ni], af[mi], acc[mi][ni], 0, 0, 0);
        }
        __syncthreads();
    }

    int colbase = blockN + wn * 64;
    if (isQ) {
        int h = colbase >> 6;
        float bias[4];
#pragma unroll
        for (int ni = 0; ni < 4; ++ni) bias[ni] = bq[colbase + ni * 16 + lr];
#pragma unroll
        for (int mi = 0; mi < 4; ++mi) {
#pragma unroll
            for (int r = 0; r < 4; ++r) {
                int m = blockM + wm * 64 + mi * 16 + quad * 4 + r;
                int b = m >> 11, s = m & 2047;
                int bh = (b << 4) + h;
                float qsq = 0.f;
#pragma unroll
                for (int ni = 0; ni < 4; ++ni) {
                    float v = acc[mi][ni][r] + bias[ni];
                    bf16 vb = (bf16)v;
                    Q[((size_t)bh * SEQ + s) * 64 + ni * 16 + lr] = vb;
                    float vr = (float)vb;
                    qsq += vr * vr;
                }
                qsq += __shfl_xor(qsq, 1);
                qsq += __shfl_xor(qsq, 2);
                qsq += __shfl_xor(qsq, 4);
                qsq += __shfl_xor(qsq, 8);
                if (lr == 0) QN[(size_t)bh * SEQ + s] = qsq;
            }
        }
    } else {
        int h = (colbase - 1024) >> 6;
        int b = blockM >> 11;
        int bh = (b << 4) + h;
        int s_base = (blockM & 2047) + wm * 64;
        const float* bvh = bv + (colbase - 1024);
#pragma unroll
        for (int ni = 0; ni < 4; ++ni) {
#pragma unroll
            for (int r = 0; r < 4; ++r) {
                int dh = ni * 16 + quad * 4 + r;
                float bias = bvh[dh];
#pragma unroll
                for (int mi = 0; mi < 4; ++mi) {
                    int s = s_base + mi * 16 + lr;
                    Vt[((size_t)bh * 64 + dh) * SEQ + s] = (f16)(acc[mi][ni][r] + bias);
                }
            }
        }
    }
}

// ---------------- attention v4: S^T orientation, register-direct PV, prefetch ----------------
// grid: x = 16 (i-tiles of 128), y = 64 (b*h). 256 threads = 4 waves x 32 rows.
// S^T = mfma(K, Q): lane holds (i=lr, j=ni*16+quad*4+rr) == A-frag of 16x16x16 MFMA.
// PV: mfma_16x16x16f16(P_frag, V_frag) with V staged as f16, pad-72 LDS rows.

__global__ __launch_bounds__(256, 4) void k_attn(const bf16* __restrict__ Q,
                                                 const f16* __restrict__ Vt,
                                                 const float* __restrict__ QN,
                                                 bf16* __restrict__ AO) {
    __shared__ bf16 Ks[64 * 64];     // xor-swizzled 16B chunks
    __shared__ f16 Vs[64 * 72];      // pad-72 rows (d-major)
    __shared__ float BBl[2048];
    __shared__ float Dl[4][32];

    int t = threadIdx.x, w = t >> 6, l = t & 63;
    int bh = blockIdx.y;
    int i0 = blockIdx.x * 128;
    const bf16* Qh = Q + (size_t)bh * SEQ * 64;
    const f16* Vh = Vt + (size_t)bh * 64 * SEQ;
    int lr = l & 15, quad = l >> 4, q8 = quad * 8, lr7 = lr & 7;

    // stage pre-scaled BB once
    {
        const float4* QN4 = (const float4*)(QN + (size_t)bh * SEQ);
        float4* BB4 = (float4*)BBl;
#pragma unroll
        for (int i = 0; i < 2; ++i) {
            float4 v = QN4[t + i * 256];
            v.x *= (SCALE * LOG2E); v.y *= (SCALE * LOG2E);
            v.z *= (SCALE * LOG2E); v.w *= (SCALE * LOG2E);
            BB4[t + i * 256] = v;
        }
    }

    // Q fragments (B-operand of S^T mfma; same row-major frag layout)
    bf16x8 af[2][2];
#pragma unroll
    for (int mi = 0; mi < 2; ++mi)
#pragma unroll
        for (int kc = 0; kc < 2; ++kc)
            af[mi][kc] = *(const bf16x8*)(Qh + (size_t)(i0 + w * 32 + mi * 16 + lr) * 64 + kc * 32 + q8);

    f32x4 oacc[2][4] = {};
    float dpart[2] = {0.f, 0.f};

    // Ks frag read offsets (A-operand rows j = ni*16+lr): base for ni=0, +ni*1024 elements
    int kb[2];
#pragma unroll
    for (int kc = 0; kc < 2; ++kc) kb[kc] = lr * 64 + (((kc * 4 + quad) ^ lr7) * 8);
    // Vs frag read offsets: rows d = di*16+lr, cols ni*16+quad*4
    int vb[4];
#pragma unroll
    for (int di = 0; di < 4; ++di) vb[di] = (di * 16 + lr) * 72 + quad * 4;

    // staging decomposition
    int sr0 = t >> 3, sc0 = t & 7;
    int sr1 = sr0 + 32;
    int ksl0 = sr0 * 64 + ((sc0 ^ (sr0 & 7)) * 8);
    int ksl1 = sr1 * 64 + ((sc0 ^ (sr1 & 7)) * 8);
    int vsl0 = sr0 * 72 + sc0 * 8;
    int vsl1 = sr1 * 72 + sc0 * 8;

    // prefetch first tile into registers
    u32x4 rk0 = *(const u32x4*)(Qh + (size_t)sr0 * 64 + sc0 * 8);
    u32x4 rk1 = *(const u32x4*)(Qh + (size_t)sr1 * 64 + sc0 * 8);
    u32x4 rv0 = *(const u32x4*)(Vh + (size_t)sr0 * SEQ + sc0 * 8);
    u32x4 rv1 = *(const u32x4*)(Vh + (size_t)sr1 * SEQ + sc0 * 8);

    const float c2s = 2.f * SCALE * LOG2E;

    for (int j0 = 0; j0 < SEQ; j0 += 64) {
        __syncthreads();
        *(u32x4*)(Ks + ksl0) = rk0;
        *(u32x4*)(Ks + ksl1) = rk1;
        *(u32x4*)(Vs + vsl0) = rv0;
        *(u32x4*)(Vs + vsl1) = rv1;
        // prefetch next tile
        int jn = j0 + 64;
        if (jn < SEQ) {
            rk0 = *(const u32x4*)(Qh + (size_t)(jn + sr0) * 64 + sc0 * 8);
            rk1 = *(const u32x4*)(Qh + (size_t)(jn + sr1) * 64 + sc0 * 8);
            rv0 = *(const u32x4*)(Vh + (size_t)sr0 * SEQ + jn + sc0 * 8);
            rv1 = *(const u32x4*)(Vh + (size_t)sr1 * SEQ + jn + sc0 * 8);
        }
        __syncthreads();

#pragma unroll
        for (int ni = 0; ni < 4; ++ni) {
            bf16x8 bk0 = *(const bf16x8*)(Ks + ni * 1024 + kb[0]);
            bf16x8 bk1 = *(const bf16x8*)(Ks + ni * 1024 + kb[1]);
            f32x4 sT0 = {}, sT1 = {};
            sT0 = __builtin_amdgcn_mfma_f32_16x16x32_bf16(bk0, af[0][0], sT0, 0, 0, 0);
            sT0 = __builtin_amdgcn_mfma_f32_16x16x32_bf16(bk1, af[0][1], sT0, 0, 0, 0);
            sT1 = __builtin_amdgcn_mfma_f32_16x16x32_bf16(bk0, af[1][0], sT1, 0, 0, 0);
            sT1 = __builtin_amdgcn_mfma_f32_16x16x32_bf16(bk1, af[1][1], sT1, 0, 0, 0);

            f32x4 bbt = *(const f32x4*)(BBl + j0 + ni * 16 + quad * 4);

            float p00 = __builtin_amdgcn_exp2f(sT0[0] * c2s - bbt[0]);
            float p01 = __builtin_amdgcn_exp2f(sT0[1] * c2s - bbt[1]);
            float p02 = __builtin_amdgcn_exp2f(sT0[2] * c2s - bbt[2]);
            float p03 = __builtin_amdgcn_exp2f(sT0[3] * c2s - bbt[3]);
            float p10 = __builtin_amdgcn_exp2f(sT1[0] * c2s - bbt[0]);
            float p11 = __builtin_amdgcn_exp2f(sT1[1] * c2s - bbt[1]);
            float p12 = __builtin_amdgcn_exp2f(sT1[2] * c2s - bbt[2]);
            float p13 = __builtin_amdgcn_exp2f(sT1[3] * c2s - bbt[3]);
            dpart[0] += (p00 + p01) + (p02 + p03);
            dpart[1] += (p10 + p11) + (p12 + p13);

            f16x2 a0 = pk_f16(p00, p01);
            f16x2 a1 = pk_f16(p02, p03);
            f16x2 b0 = pk_f16(p10, p11);
            f16x2 b1 = pk_f16(p12, p13);
            f16x4 pf0 = {a0[0], a0[1], a1[0], a1[1]};
            f16x4 pf1 = {b0[0], b0[1], b1[0], b1[1]};

#pragma unroll
            for (int di = 0; di < 4; ++di) {
                f16x4 vf = *(const f16x4*)(Vs + vb[di] + ni * 16);
                oacc[0][di] = __builtin_amdgcn_mfma_f32_16x16x16f16(pf0, vf, oacc[0][di], 0, 0, 0);
                oacc[1][di] = __builtin_amdgcn_mfma_f32_16x16x16f16(pf1, vf, oacc[1][di], 0, 0, 0);
            }
        }
    }

    // denominators: lane holds partial for i = mi*16+lr over its quad's j's -> reduce quads
#pragma unroll
    for (int mi = 0; mi < 2; ++mi) {
        float ds = dpart[mi];
        ds += __shfl_xor(ds, 16);
        ds += __shfl_xor(ds, 32);
        if (quad == 0) Dl[w][mi * 16 + lr] = ds;
    }
    __syncthreads();

    // epilogue: oacc rows i = mi*16 + quad*4 + r, cols d = di*16 + lr
    int b = bh >> 4, h = bh & 15;
#pragma unroll
    for (int mi = 0; mi < 2; ++mi) {
#pragma unroll
        for (int r = 0; r < 4; ++r) {
            float inv = 1.f / Dl[w][mi * 16 + quad * 4 + r];
            int s = i0 + w * 32 + mi * 16 + quad * 4 + r;
#pragma unroll
            for (int di = 0; di < 4; ++di) {
                AO[((size_t)(b * SEQ + s)) * 1024 + h * 64 + di * 16 + lr] = (bf16)(oacc[mi][di][r] * inv);
            }
        }
    }
}

// ---------------- GEMM 3: out = AO @ Wo + bo ----------------

__global__ __launch_bounds__(256) void k_gemm_out(const bf16* __restrict__ AO,
                                                  const bf16* __restrict__ Wot,
                                                  const float* __restrict__ bo,
                                                  float* __restrict__ out) {
    constexpr int K = 1024;
    __shared__ bf16 As[128 * 32];
    __shared__ bf16 Bs[128 * 32];
    int t = threadIdx.x, w = t >> 6, l = t & 63;
    int blockN = blockIdx.x * 128, blockM = blockIdx.y * 128;
    int wm = w & 1, wn = w >> 1;
    int lr = l & 15, quad = l >> 4, q8 = quad * 8;
    int skcol = (l & 3) * 8;

    f32x4 acc[4][4] = {};
    const bf16* Ab = AO + (size_t)blockM * K;
    const bf16* Bb = Wot + (size_t)blockN * K;

    for (int k0 = 0; k0 < K; k0 += 32) {
#pragma unroll
        for (int c2 = 0; c2 < 2; ++c2) {
            int c = 2 * w + c2;
            int row = c * 16 + (l >> 2);
            gl_lds16(Ab + (size_t)row * K + k0 + skcol, As + c * 512);
            gl_lds16(Bb + (size_t)row * K + k0 + skcol, Bs + c * 512);
        }
        __syncthreads();
        const bf16* Aw = As + wm * 64 * 32;
        const bf16* Bw = Bs + wn * 64 * 32;
        bf16x8 af[4], bfr[4];
#pragma unroll
        for (int mi = 0; mi < 4; ++mi) af[mi] = *(const bf16x8*)(Aw + (mi * 16 + lr) * 32 + q8);
#pragma unroll
        for (int ni = 0; ni < 4; ++ni) bfr[ni] = *(const bf16x8*)(Bw + (ni * 16 + lr) * 32 + q8);
#pragma unroll
        for (int mi = 0; mi < 4; ++mi)
#pragma unroll
            for (int ni = 0; ni < 4; ++ni)
                acc[mi][ni] = __builtin_amdgcn_mfma_f32_16x16x32_bf16(af[mi], bfr[ni], acc[mi][ni], 0, 0, 0);
        __syncthreads();
    }

    int colbase = blockN + wn * 64;
    float bias[4];
#pragma unroll
    for (int ni = 0; ni < 4; ++ni) bias[ni] = bo[colbase + ni * 16 + lr];
#pragma unroll
    for (int mi = 0; mi < 4; ++mi) {
#pragma unroll
        for (int r = 0; r < 4; ++r) {
            int m = blockM + wm * 64 + mi * 16 + quad * 4 + r;
#pragma unroll
            for (int ni = 0; ni < 4; ++ni) {
                out[(size_t)m * 1024 + colbase + ni * 16 + lr] = acc[mi][ni][r] + bias[ni];
            }
        }
    }
}

// ---------------- launch ----------------

extern "C" void kernel_launch(void* const* d_in, const int* in_sizes, int n_in,
                              void* d_out, int out_size, void* d_ws, size_t ws_size,
                              hipStream_t stream) {
    const float* x  = (const float*)d_in[0];
    const float* Wq = (const float*)d_in[1];
    const float* bq = (const float*)d_in[2];
    const float* Wv = (const float*)d_in[3];
    const float* bv = (const float*)d_in[4];
    const float* Wo = (const float*)d_in[5];
    const float* bo = (const float*)d_in[6];
    float* out = (float*)d_out;

    char* ws = (char*)d_ws;
    bf16* Xb   = (bf16*)ws;                          // 16 MB (reused as AO)
    bf16* Wqvt = (bf16*)(ws + (size_t)(16 << 20));   // 4 MB
    bf16* Wot  = (bf16*)(ws + (size_t)(20 << 20));   // 2 MB
    bf16* Qb   = (bf16*)(ws + (size_t)(22 << 20));   // 16 MB
    f16*  Vtb  = (f16*)(ws + (size_t)(38 << 20));    // 16 MB
    float* QN  = (float*)(ws + (size_t)(54 << 20));  // 0.5 MB
    bf16* AO   = Xb;

    k_cast_x<<<8192, 256, 0, stream>>>((const float4*)x, (bf16x4*)Xb);
    dim3 tb(32, 8);
    k_transpose_cast<<<dim3(32, 32), tb, 0, stream>>>(Wq, Wqvt);
    k_transpose_cast<<<dim3(32, 32), tb, 0, stream>>>(Wv, Wqvt + 1024 * 1024);
    k_transpose_cast<<<dim3(32, 32), tb, 0, stream>>>(Wo, Wot);
    k_gemm_qv<<<dim3(16, 64), 256, 0, stream>>>(Xb, Wqvt, bq, bv, Qb, Vtb, QN);
    k_attn<<<dim3(16, 64), 256, 0, stream>>>(Qb, Vtb, QN, AO);
    k_gemm_out<<<dim3(8, 64), 256, 0, stream>>>(AO, Wot, bo, out);
}

// Round 6
// 290.434 us; speedup vs baseline: 1.8774x; 1.0569x over previous
//
#include <hip/hip_runtime.h>
#include <hip/hip_bf16.h>

#define SEQ 2048
#define SCALE 0.125f
#define LOG2E 1.4426950408889634f
// sqrt(2*SCALE*LOG2E): both S operands pre-scaled by this -> S arrives *2*SCALE*LOG2E
#define ALPHA 0.6005612049f

typedef __bf16 bf16;
typedef __bf16 bf16x4 __attribute__((ext_vector_type(4)));
typedef __bf16 bf16x8 __attribute__((ext_vector_type(8)));
typedef _Float16 f16;
typedef _Float16 f16x2 __attribute__((ext_vector_type(2)));
typedef _Float16 f16x4 __attribute__((ext_vector_type(4)));
typedef _Float16 f16x8 __attribute__((ext_vector_type(8)));
typedef float f32x4 __attribute__((ext_vector_type(4)));
typedef unsigned int u32;
typedef unsigned int u32x2 __attribute__((ext_vector_type(2)));
typedef unsigned int u32x4 __attribute__((ext_vector_type(4)));

__device__ __forceinline__ f16x2 pk_f16(float a, float b) {
    return __builtin_bit_cast(f16x2, __builtin_amdgcn_cvt_pkrtz(a, b));
}

__device__ __forceinline__ void gl_lds16(const void* g, void* l) {
    __builtin_amdgcn_global_load_lds((const __attribute__((address_space(1))) u32*)g,
                                     (__attribute__((address_space(3))) u32*)l, 16, 0, 0);
}

// ---------------- prep kernels ----------------

__global__ __launch_bounds__(256) void k_cast_x(const float4* __restrict__ x,
                                                bf16x4* __restrict__ xb) {
    int t = blockIdx.x * 256 + threadIdx.x;
    float4 f = x[t];
    bf16x4 o;
    o[0] = (bf16)f.x; o[1] = (bf16)f.y; o[2] = (bf16)f.z; o[3] = (bf16)f.w;
    xb[t] = o;
}

__global__ __launch_bounds__(256) void k_transpose_cast(const float* __restrict__ src,
                                                        bf16* __restrict__ dst) {
    __shared__ float tile[32][33];
    int bx = blockIdx.x * 32;
    int by = blockIdx.y * 32;
    int tx = threadIdx.x;
    int ty = threadIdx.y;
#pragma unroll
    for (int j = 0; j < 32; j += 8)
        tile[ty + j][tx] = src[(size_t)(by + ty + j) * 1024 + bx + tx];
    __syncthreads();
#pragma unroll
    for (int j = 0; j < 32; j += 8)
        dst[(size_t)(bx + ty + j) * 1024 + by + tx] = (bf16)tile[tx][ty + j];
}

// ---------------- GEMM 1: QV = Xb @ [Wq|Wv] + bias ----------------
// Q blocks: C = A*B^T -> Q[bh][s][dh] stored PRE-SCALED by ALPHA (bf16),
//           QN[bh][s] = -0.5 * ||q_scaled||^2 (ready as exp2 C-init).
// V blocks: swapped operands -> registers hold Vt tiles -> Vt[bh][dh][s] in f16.

__global__ __launch_bounds__(256) void k_gemm_qv(const bf16* __restrict__ Xb,
                                                 const bf16* __restrict__ Wqvt,
                                                 const float* __restrict__ bq,
                                                 const float* __restrict__ bv,
                                                 bf16* __restrict__ Q,
                                                 f16* __restrict__ Vt,
                                                 float* __restrict__ QN) {
    constexpr int K = 1024;
    __shared__ bf16 As[128 * 32];
    __shared__ bf16 Bs[128 * 32];
    int t = threadIdx.x, w = t >> 6, l = t & 63;
    int blockN = blockIdx.x * 128, blockM = blockIdx.y * 128;
    int wm = w & 1, wn = w >> 1;
    int lr = l & 15, quad = l >> 4, q8 = quad * 8;
    int skcol = (l & 3) * 8;
    bool isQ = blockN < 1024;

    f32x4 acc[4][4] = {};
    const bf16* Ab = Xb + (size_t)blockM * K;
    const bf16* Bb = Wqvt + (size_t)blockN * K;

    for (int k0 = 0; k0 < K; k0 += 32) {
#pragma unroll
        for (int c2 = 0; c2 < 2; ++c2) {
            int c = 2 * w + c2;
            int row = c * 16 + (l >> 2);
            gl_lds16(Ab + (size_t)row * K + k0 + skcol, As + c * 512);
            gl_lds16(Bb + (size_t)row * K + k0 + skcol, Bs + c * 512);
        }
        __syncthreads();
        const bf16* Aw = As + wm * 64 * 32;
        const bf16* Bw = Bs + wn * 64 * 32;
        bf16x8 af[4], bfr[4];
#pragma unroll
        for (int mi = 0; mi < 4; ++mi) af[mi] = *(const bf16x8*)(Aw + (mi * 16 + lr) * 32 + q8);
#pragma unroll
        for (int ni = 0; ni < 4; ++ni) bfr[ni] = *(const bf16x8*)(Bw + (ni * 16 + lr) * 32 + q8);
        if (isQ) {
#pragma unroll
            for (int mi = 0; mi < 4; ++mi)
#pragma unroll
                for (int ni = 0; ni < 4; ++ni)
                    acc[mi][ni] = __builtin_amdgcn_mfma_f32_16x16x32_bf16(af[mi], bfr[ni], acc[mi][ni], 0, 0, 0);
        } else {
#pragma unroll
            for (int mi = 0; mi < 4; ++mi)
#pragma unroll
                for (int ni = 0; ni < 4; ++ni)
                    acc[mi][ni] = __builtin_amdgcn_mfma_f32_16x16x32_bf16(bfr[ni], af[mi], acc[mi][ni], 0, 0, 0);
        }
        __syncthreads();
    }

    int colbase = blockN + wn * 64;
    if (isQ) {
        int h = colbase >> 6;
        float bias[4];
#pragma unroll
        for (int ni = 0; ni < 4; ++ni) bias[ni] = bq[colbase + ni * 16 + lr];
#pragma unroll
        for (int mi = 0; mi < 4; ++mi) {
#pragma unroll
            for (int r = 0; r < 4; ++r) {
                int m = blockM + wm * 64 + mi * 16 + quad * 4 + r;
                int b = m >> 11, s = m & 2047;
                int bh = (b << 4) + h;
                float qsq = 0.f;
#pragma unroll
                for (int ni = 0; ni < 4; ++ni) {
                    float v = (acc[mi][ni][r] + bias[ni]) * ALPHA;
                    bf16 vb = (bf16)v;
                    Q[((size_t)bh * SEQ + s) * 64 + ni * 16 + lr] = vb;
                    float vr = (float)vb;
                    qsq += vr * vr;
                }
                qsq += __shfl_xor(qsq, 1);
                qsq += __shfl_xor(qsq, 2);
                qsq += __shfl_xor(qsq, 4);
                qsq += __shfl_xor(qsq, 8);
                if (lr == 0) QN[(size_t)bh * SEQ + s] = -0.5f * qsq;
            }
        }
    } else {
        int h = (colbase - 1024) >> 6;
        int b = blockM >> 11;
        int bh = (b << 4) + h;
        int s_base = (blockM & 2047) + wm * 64;
        const float* bvh = bv + (colbase - 1024);
#pragma unroll
        for (int ni = 0; ni < 4; ++ni) {
#pragma unroll
            for (int r = 0; r < 4; ++r) {
                int dh = ni * 16 + quad * 4 + r;
                float bias = bvh[dh];
#pragma unroll
                for (int mi = 0; mi < 4; ++mi) {
                    int s = s_base + mi * 16 + lr;
                    Vt[((size_t)bh * 64 + dh) * SEQ + s] = (f16)(acc[mi][ni][r] + bias);
                }
            }
        }
    }
}

// ---------------- attention v5 ----------------
// grid: x = 16 (i-tiles of 128), y = 64 (b*h). 256 threads = 4 waves x 32 rows.
// S^T = mfma(K, Q, C=-0.5||q_j||^2) with pre-scaled Q -> p = exp2(sacc) directly.
// Denominator via mfma(pf, ones) -> no shuffles. Vs paired-chunk swizzled layout:
// chunk cp=np*4+quad holds cols {np*32+ni1*16+quad*4+t : ni1 in 0..1, t in 0..3},
// stored at chunk (cp ^ (row&7)) -> conflict-free b64 staging + b128 frag reads.

__global__ __launch_bounds__(256, 4) void k_attn(const bf16* __restrict__ Q,
                                                 const f16* __restrict__ Vt,
                                                 const float* __restrict__ QN,
                                                 bf16* __restrict__ AO) {
    __shared__ bf16 Ks[64 * 64];     // xor-swizzled 16B chunks
    __shared__ f16 Vs[64 * 64];      // paired-chunk swizzled (see header)
    __shared__ float BBl[2048];

    int t = threadIdx.x, w = t >> 6, l = t & 63;
    int bh = blockIdx.y;
    int i0 = blockIdx.x * 128;
    const bf16* Qh = Q + (size_t)bh * SEQ * 64;
    const f16* Vh = Vt + (size_t)bh * 64 * SEQ;
    int lr = l & 15, quad = l >> 4, q8 = quad * 8, lr7 = lr & 7;

    // stage QN (already -0.5*||q'||^2) once
    {
        const float4* QN4 = (const float4*)(QN + (size_t)bh * SEQ);
        float4* BB4 = (float4*)BBl;
        BB4[t] = QN4[t];
        BB4[t + 256] = QN4[t + 256];
    }

    // Q fragments (pre-scaled)
    bf16x8 af[2][2];
#pragma unroll
    for (int mi = 0; mi < 2; ++mi)
#pragma unroll
        for (int kc = 0; kc < 2; ++kc)
            af[mi][kc] = *(const bf16x8*)(Qh + (size_t)(i0 + w * 32 + mi * 16 + lr) * 64 + kc * 32 + q8);

    f32x4 oacc[2][4] = {};
    f32x4 dacc[2] = {};
    const f16x4 ones = {(f16)1.f, (f16)1.f, (f16)1.f, (f16)1.f};

    // Ks frag offsets (A-operand rows j = ni*16+lr)
    int kb[2];
#pragma unroll
    for (int kc = 0; kc < 2; ++kc) kb[kc] = lr * 64 + (((kc * 4 + quad) ^ lr7) * 8);
    // Vs frag offsets: row (di*16+lr), chunk (np*4+quad)^lr7
    int voff[4];
#pragma unroll
    for (int di = 0; di < 4; ++di) voff[di] = (di * 16 + lr) * 64;
    int npo[2];
#pragma unroll
    for (int np = 0; np < 2; ++np) npo[np] = ((np * 4 + quad) ^ lr7) * 8;

    // staging decomposition
    int sr0 = t >> 3, sc = t & 7;
    int sr1 = sr0 + 32;
    int ksl0 = sr0 * 64 + ((sc ^ (sr0 & 7)) * 8);
    int ksl1 = sr1 * 64 + ((sc ^ (sr1 & 7)) * 8);
    // V write targets: global 16B covers j = sc*8..sc*8+7 -> two 8B pieces
    int np_s = sc >> 2, ni1_s = (sc >> 1) & 1, q0_s = (sc & 1) * 2;
    int cpA = np_s * 4 + q0_s, cpB = cpA + 1;
    int vdA0 = sr0 * 64 + ((cpA ^ (sr0 & 7)) * 8) + ni1_s * 4;
    int vdB0 = sr0 * 64 + ((cpB ^ (sr0 & 7)) * 8) + ni1_s * 4;
    int vdA1 = sr1 * 64 + ((cpA ^ (sr1 & 7)) * 8) + ni1_s * 4;
    int vdB1 = sr1 * 64 + ((cpB ^ (sr1 & 7)) * 8) + ni1_s * 4;

    // prefetch first tile into registers
    u32x4 rk0 = *(const u32x4*)(Qh + (size_t)sr0 * 64 + sc * 8);
    u32x4 rk1 = *(const u32x4*)(Qh + (size_t)sr1 * 64 + sc * 8);
    u32x4 rv0 = *(const u32x4*)(Vh + (size_t)sr0 * SEQ + sc * 8);
    u32x4 rv1 = *(const u32x4*)(Vh + (size_t)sr1 * SEQ + sc * 8);

    for (int j0 = 0; j0 < SEQ; j0 += 64) {
        __syncthreads();
        *(u32x4*)(Ks + ksl0) = rk0;
        *(u32x4*)(Ks + ksl1) = rk1;
        {
            u32x2 lo0 = {rv0[0], rv0[1]}, hi0 = {rv0[2], rv0[3]};
            u32x2 lo1 = {rv1[0], rv1[1]}, hi1 = {rv1[2], rv1[3]};
            *(u32x2*)(Vs + vdA0) = lo0;
            *(u32x2*)(Vs + vdB0) = hi0;
            *(u32x2*)(Vs + vdA1) = lo1;
            *(u32x2*)(Vs + vdB1) = hi1;
        }
        // prefetch next tile
        int jn = j0 + 64;
        if (jn < SEQ) {
            rk0 = *(const u32x4*)(Qh + (size_t)(jn + sr0) * 64 + sc * 8);
            rk1 = *(const u32x4*)(Qh + (size_t)(jn + sr1) * 64 + sc * 8);
            rv0 = *(const u32x4*)(Vh + (size_t)sr0 * SEQ + jn + sc * 8);
            rv1 = *(const u32x4*)(Vh + (size_t)sr1 * SEQ + jn + sc * 8);
        }
        __syncthreads();

#pragma unroll
        for (int np = 0; np < 2; ++np) {
            f16x4 pf[2][2];   // [mi][ni1]
#pragma unroll
            for (int ni1 = 0; ni1 < 2; ++ni1) {
                int ni = np * 2 + ni1;
                bf16x8 bk0 = *(const bf16x8*)(Ks + ni * 1024 + kb[0]);
                bf16x8 bk1 = *(const bf16x8*)(Ks + ni * 1024 + kb[1]);
                f32x4 bbt = *(const f32x4*)(BBl + j0 + ni * 16 + quad * 4);
                f32x4 sT0 = bbt, sT1 = bbt;
                sT0 = __builtin_amdgcn_mfma_f32_16x16x32_bf16(bk0, af[0][0], sT0, 0, 0, 0);
                sT0 = __builtin_amdgcn_mfma_f32_16x16x32_bf16(bk1, af[0][1], sT0, 0, 0, 0);
                sT1 = __builtin_amdgcn_mfma_f32_16x16x32_bf16(bk0, af[1][0], sT1, 0, 0, 0);
                sT1 = __builtin_amdgcn_mfma_f32_16x16x32_bf16(bk1, af[1][1], sT1, 0, 0, 0);

                float p00 = __builtin_amdgcn_exp2f(sT0[0]);
                float p01 = __builtin_amdgcn_exp2f(sT0[1]);
                float p02 = __builtin_amdgcn_exp2f(sT0[2]);
                float p03 = __builtin_amdgcn_exp2f(sT0[3]);
                float p10 = __builtin_amdgcn_exp2f(sT1[0]);
                float p11 = __builtin_amdgcn_exp2f(sT1[1]);
                float p12 = __builtin_amdgcn_exp2f(sT1[2]);
                float p13 = __builtin_amdgcn_exp2f(sT1[3]);

                f16x2 a0 = pk_f16(p00, p01);
                f16x2 a1 = pk_f16(p02, p03);
                f16x2 b0 = pk_f16(p10, p11);
                f16x2 b1 = pk_f16(p12, p13);
                pf[0][ni1] = f16x4{a0[0], a0[1], a1[0], a1[1]};
                pf[1][ni1] = f16x4{b0[0], b0[1], b1[0], b1[1]};

                dacc[0] = __builtin_amdgcn_mfma_f32_16x16x16f16(pf[0][ni1], ones, dacc[0], 0, 0, 0);
                dacc[1] = __builtin_amdgcn_mfma_f32_16x16x16f16(pf[1][ni1], ones, dacc[1], 0, 0, 0);
            }
#pragma unroll
            for (int di = 0; di < 4; ++di) {
                f16x8 vf8 = *(const f16x8*)(Vs + voff[di] + npo[np]);
                f16x4 vlo = __builtin_shufflevector(vf8, vf8, 0, 1, 2, 3);
                f16x4 vhi = __builtin_shufflevector(vf8, vf8, 4, 5, 6, 7);
                oacc[0][di] = __builtin_amdgcn_mfma_f32_16x16x16f16(pf[0][0], vlo, oacc[0][di], 0, 0, 0);
                oacc[1][di] = __builtin_amdgcn_mfma_f32_16x16x16f16(pf[1][0], vlo, oacc[1][di], 0, 0, 0);
                oacc[0][di] = __builtin_amdgcn_mfma_f32_16x16x16f16(pf[0][1], vhi, oacc[0][di], 0, 0, 0);
                oacc[1][di] = __builtin_amdgcn_mfma_f32_16x16x16f16(pf[1][1], vhi, oacc[1][di], 0, 0, 0);
            }
        }
    }

    // epilogue: dacc[mi][r] holds denom for row i = mi*16 + quad*4 + r (all lr copies)
    int b = bh >> 4, h = bh & 15;
#pragma unroll
    for (int mi = 0; mi < 2; ++mi) {
#pragma unroll
        for (int r = 0; r < 4; ++r) {
            float inv = 1.f / dacc[mi][r];
            int s = i0 + w * 32 + mi * 16 + quad * 4 + r;
#pragma unroll
            for (int di = 0; di < 4; ++di) {
                AO[((size_t)(b * SEQ + s)) * 1024 + h * 64 + di * 16 + lr] = (bf16)(oacc[mi][di][r] * inv);
            }
        }
    }
}

// ---------------- GEMM 3: out = AO @ Wo + bo ----------------

__global__ __launch_bounds__(256) void k_gemm_out(const bf16* __restrict__ AO,
                                                  const bf16* __restrict__ Wot,
                                                  const float* __restrict__ bo,
                                                  float* __restrict__ out) {
    constexpr int K = 1024;
    __shared__ bf16 As[128 * 32];
    __shared__ bf16 Bs[128 * 32];
    int t = threadIdx.x, w = t >> 6, l = t & 63;
    int blockN = blockIdx.x * 128, blockM = blockIdx.y * 128;
    int wm = w & 1, wn = w >> 1;
    int lr = l & 15, quad = l >> 4, q8 = quad * 8;
    int skcol = (l & 3) * 8;

    f32x4 acc[4][4] = {};
    const bf16* Ab = AO + (size_t)blockM * K;
    const bf16* Bb = Wot + (size_t)blockN * K;

    for (int k0 = 0; k0 < K; k0 += 32) {
#pragma unroll
        for (int c2 = 0; c2 < 2; ++c2) {
            int c = 2 * w + c2;
            int row = c * 16 + (l >> 2);
            gl_lds16(Ab + (size_t)row * K + k0 + skcol, As + c * 512);
            gl_lds16(Bb + (size_t)row * K + k0 + skcol, Bs + c * 512);
        }
        __syncthreads();
        const bf16* Aw = As + wm * 64 * 32;
        const bf16* Bw = Bs + wn * 64 * 32;
        bf16x8 af[4], bfr[4];
#pragma unroll
        for (int mi = 0; mi < 4; ++mi) af[mi] = *(const bf16x8*)(Aw + (mi * 16 + lr) * 32 + q8);
#pragma unroll
        for (int ni = 0; ni < 4; ++ni) bfr[ni] = *(const bf16x8*)(Bw + (ni * 16 + lr) * 32 + q8);
#pragma unroll
        for (int mi = 0; mi < 4; ++mi)
#pragma unroll
            for (int ni = 0; ni < 4; ++ni)
                acc[mi][ni] = __builtin_amdgcn_mfma_f32_16x16x32_bf16(af[mi], bfr[ni], acc[mi][ni], 0, 0, 0);
        __syncthreads();
    }

    int colbase = blockN + wn * 64;
    float bias[4];
#pragma unroll
    for (int ni = 0; ni < 4; ++ni) bias[ni] = bo[colbase + ni * 16 + lr];
#pragma unroll
    for (int mi = 0; mi < 4; ++mi) {
#pragma unroll
        for (int r = 0; r < 4; ++r) {
            int m = blockM + wm * 64 + mi * 16 + quad * 4 + r;
#pragma unroll
            for (int ni = 0; ni < 4; ++ni) {
                out[(size_t)m * 1024 + colbase + ni * 16 + lr] = acc[mi][ni][r] + bias[ni];
            }
        }
    }
}

// ---------------- launch ----------------

extern "C" void kernel_launch(void* const* d_in, const int* in_sizes, int n_in,
                              void* d_out, int out_size, void* d_ws, size_t ws_size,
                              hipStream_t stream) {
    const float* x  = (const float*)d_in[0];
    const float* Wq = (const float*)d_in[1];
    const float* bq = (const float*)d_in[2];
    const float* Wv = (const float*)d_in[3];
    const float* bv = (const float*)d_in[4];
    const float* Wo = (const float*)d_in[5];
    const float* bo = (const float*)d_in[6];
    float* out = (float*)d_out;

    char* ws = (char*)d_ws;
    bf16* Xb   = (bf16*)ws;                          // 16 MB (reused as AO)
    bf16* Wqvt = (bf16*)(ws + (size_t)(16 << 20));   // 4 MB
    bf16* Wot  = (bf16*)(ws + (size_t)(20 << 20));   // 2 MB
    bf16* Qb   = (bf16*)(ws + (size_t)(22 << 20));   // 16 MB
    f16*  Vtb  = (f16*)(ws + (size_t)(38 << 20));    // 16 MB
    float* QN  = (float*)(ws + (size_t)(54 << 20));  // 0.5 MB
    bf16* AO   = Xb;

    k_cast_x<<<8192, 256, 0, stream>>>((const float4*)x, (bf16x4*)Xb);
    dim3 tb(32, 8);
    k_transpose_cast<<<dim3(32, 32), tb, 0, stream>>>(Wq, Wqvt);
    k_transpose_cast<<<dim3(32, 32), tb, 0, stream>>>(Wv, Wqvt + 1024 * 1024);
    k_transpose_cast<<<dim3(32, 32), tb, 0, stream>>>(Wo, Wot);
    k_gemm_qv<<<dim3(16, 64), 256, 0, stream>>>(Xb, Wqvt, bq, bv, Qb, Vtb, QN);
    k_attn<<<dim3(16, 64), 256, 0, stream>>>(Qb, Vtb, QN, AO);
    k_gemm_out<<<dim3(8, 64), 256, 0, stream>>>(AO, Wot, bo, out);
}